// Round 5
// baseline (1223.455 us; speedup 1.0000x reference)
//
#include <hip/hip_runtime.h>
#include <hip/hip_bf16.h>
#include <cmath>

#define TSTEPS 128
#define NENVS  64
#define HID    1024
#define G3     3072
#define MROWS  8192   // T*N

typedef unsigned short u16;
typedef unsigned long long u64;
typedef short bf8 __attribute__((ext_vector_type(8)));   // 8 bf16 = 4 VGPRs
typedef float f4  __attribute__((ext_vector_type(4)));   // MFMA acc
typedef u16  us4  __attribute__((ext_vector_type(4)));

#define FLAG_STRIDE 32   // u32s between flags (128 B) — no same-line RMW collisions

static __device__ inline u16 f2bf(float f) {
  __hip_bfloat16 h = __float2bfloat16(f);   // RNE
  return *reinterpret_cast<u16*>(&h);
}
static __device__ inline float bf2f(u16 v) {
  __hip_bfloat16 h = *reinterpret_cast<__hip_bfloat16*>(&v);
  return __bfloat162float(h);
}

// async global->LDS, 16B per lane; LDS dest = wave-uniform base + lane*16
static __device__ inline void gload16(const u16* g, u16* l) {
  __builtin_amdgcn_global_load_lds(
      (const __attribute__((address_space(1))) void*)g,
      (__attribute__((address_space(3))) void*)l, 16, 0, 0);
}

// ---------------------------------------------------------------------------
// fp32 -> bf16 cast, 4 elements/thread
__global__ __launch_bounds__(256) void k_cast4(const float4* __restrict__ src,
                                               us4* __restrict__ dst, int n4) {
  int i = blockIdx.x * 256 + threadIdx.x;
  if (i < n4) {
    float4 v = src[i];
    us4 o = { f2bf(v.x), f2bf(v.y), f2bf(v.z), f2bf(v.w) };
    dst[i] = o;
  }
}

// zero the flag array (8192 u32 = 32 KB); runtime's end-of-kernel writeback
// makes the zeros MALL/DRAM-visible before the scan.
__global__ __launch_bounds__(256) void k_zerofl(unsigned* __restrict__ p) {
  p[blockIdx.x * 256 + threadIdx.x] = 0u;
}

// out_tail[n][k] = float(featb_last[n][k])
__global__ __launch_bounds__(256) void k_tail(const u16* __restrict__ featb,
                                              float* __restrict__ dst) {
  __builtin_amdgcn_fence(__ATOMIC_ACQUIRE, "agent");   // defensive: kill stale lines
  int i = blockIdx.x * 256 + threadIdx.x;   // 0..65535
  dst[i] = bf2f(featb[(size_t)(TSTEPS - 1) * NENVS * HID + i]);
}

// ---------------------------------------------------------------------------
// bf16 MFMA GEMM: C[M][N] = A[M][1024] . B[N][1024]^T + bias (+relu)
// 128x128 tile/block, BK=32, 4 waves in 2x2. 2-phase double-buffered LDS,
// __launch_bounds__(256,4) co-residency. FROZEN this round (R3/R4 changes
// were neutral; no per-dispatch evidence to steer further edits).
// SWZ: bijective XCD-chunk swizzle (requires nwg % 8 == 0).
template<typename CT, int BIAS_PER_N, int RELU, int SWZ>
__global__ __launch_bounds__(256, 4) void k_gemm_bf16(const u16* __restrict__ A,
                                                      const u16* __restrict__ B,
                                                      const float* __restrict__ bias,
                                                      CT* __restrict__ C, int ldc) {
  __builtin_amdgcn_fence(__ATOMIC_ACQUIRE, "agent");   // defensive (cheap, once)
  __shared__ u16 ldsA[2][128 * 32];    // [buf][row 128][k 32], 2 x 8 KB
  __shared__ u16 ldsB[2][128 * 32];
  const int t = threadIdx.x, wave = t >> 6, lane = t & 63;
  const int quad = lane >> 4, l16 = lane & 15;
  const int wm = wave >> 1, wn = wave & 1;       // 2x2 wave grid
  int bx = blockIdx.x, by = blockIdx.y;
  if (SWZ) {
    const unsigned nwg = gridDim.x * gridDim.y;
    const unsigned L = (unsigned)by * gridDim.x + bx;
    const unsigned w = (L & 7u) * (nwg >> 3) + (L >> 3);   // XCD gets contiguous chunk
    bx = (int)(w % gridDim.x); by = (int)(w / gridDim.x);
  }
  const int m0 = by * 128;
  const int n0 = bx * 128;

  // staging identity: chunk c = 16B = 8 u16; tile = 512 chunks = [row=c>>2][k8=c&3]
  const int c   = wave * 128 + lane;
  const int row = c >> 2, k8 = c & 3;
  const u16* gA0 = A + (size_t)(m0 + row) * HID + k8 * 8;
  const u16* gA1 = gA0 + (size_t)16 * HID;       // chunk c+64 -> row+16, same k8
  const u16* gB0 = B + (size_t)(n0 + row) * HID + k8 * 8;
  const u16* gB1 = gB0 + (size_t)16 * HID;
  const int lw = wave * 1024;                    // wave-uniform LDS chunk base (u16)

  f4 acc[4][4];
#pragma unroll
  for (int mt = 0; mt < 4; ++mt)
#pragma unroll
    for (int nt = 0; nt < 4; ++nt) acc[mt][nt] = (f4){0.f, 0.f, 0.f, 0.f};

  const int aoff0 = (wm * 64 + l16) * 32 + quad * 8;
  const int boff0 = (wn * 64 + l16) * 32 + quad * 8;

  // prologue: stage tile 0 into buf 0
  gload16(gA0, &ldsA[0][lw]);
  gload16(gA1, &ldsA[0][lw + 512]);
  gload16(gB0, &ldsB[0][lw]);
  gload16(gB1, &ldsB[0][lw + 512]);
  __syncthreads();                               // vmcnt(0) drain + barrier

  int cur = 0;
  for (int kb = 0; kb < 32; ++kb) {
    if (kb < 31) {                               // stage NEXT tile into other buf
      const int ko = (kb + 1) * 32;
      const int nb = cur ^ 1;
      gload16(gA0 + ko, &ldsA[nb][lw]);
      gload16(gA1 + ko, &ldsA[nb][lw + 512]);
      gload16(gB0 + ko, &ldsB[nb][lw]);
      gload16(gB1 + ko, &ldsB[nb][lw + 512]);
    }
    bf8 af[4], bfr[4];
#pragma unroll
    for (int mt = 0; mt < 4; ++mt)
      af[mt] = *(const bf8*)(&ldsA[cur][0] + aoff0 + mt * 16 * 32);
#pragma unroll
    for (int nt = 0; nt < 4; ++nt)
      bfr[nt] = *(const bf8*)(&ldsB[cur][0] + boff0 + nt * 16 * 32);
#pragma unroll
    for (int mt = 0; mt < 4; ++mt)
#pragma unroll
      for (int nt = 0; nt < 4; ++nt)
        acc[mt][nt] = __builtin_amdgcn_mfma_f32_16x16x32_bf16(
            af[mt], bfr[nt], acc[mt][nt], 0, 0, 0);
    if (kb < 31) {
      __syncthreads();                           // drains stage of kb+1, guards buf reuse
      cur ^= 1;
    }
  }

#pragma unroll
  for (int mt = 0; mt < 4; ++mt)
#pragma unroll
    for (int nt = 0; nt < 4; ++nt) {
      const int n = n0 + wn * 64 + nt * 16 + l16;
      const float bn = BIAS_PER_N ? bias[n] : 0.f;
#pragma unroll
      for (int r = 0; r < 4; ++r) {
        const int m = m0 + wm * 64 + mt * 16 + quad * 4 + r;
        float v = acc[mt][nt][r] + (BIAS_PER_N ? bn : bias[m]);
        if (RELU) v = fmaxf(v, 0.f);
        if constexpr (sizeof(CT) == 2)
          C[(size_t)m * ldc + n] = (CT)f2bf(v);
        else
          C[(size_t)m * ldc + n] = v;
      }
    }
}

// ---------------------------------------------------------------------------
// MFMA GRU scan. 4 teams x 64 blocks; team tm owns envs tm*16..+15; block =
// 16 envs x 16 j (wave = 4 j). This round: publish via agent-scope atomic
// STORE (sc-bits -> MALL-direct, no RMW, no return payload — half the MALL
// occupancy of the old returning exchange; vmcnt retirement = accepted at
// MALL, same ack semantics). Counted-vmcnt barrier: gi/done prefetch (4
// loads) issued AFTER the h store, order pinned by memory-clobbered asm;
// s_waitcnt vmcnt(4) drains exactly the h store while the prefetch stays in
// flight under the flag/poll leg. Readers unchanged: pristine plain cached
// loads miss everywhere and fill current data from MALL.
__global__ __launch_bounds__(256, 1) void k_gru_mfma(
    const u16*  __restrict__ giTb,          // [3072][8192] bf16
    const float* __restrict__ done,         // [8192]
    const float* __restrict__ Whh,          // [3072][1024]
    const float* __restrict__ bhh,          // [3072]
    const float* __restrict__ hxs,          // [64][1024] fp32
    const u16*  __restrict__ hb0,           // [64][1024] bf16 h0
    u16*        __restrict__ featb,         // [8192][1024] bf16, PRISTINE region
    unsigned*   __restrict__ flags) {       // [256*FLAG_STRIDE] u32, zeroed
  __builtin_amdgcn_fence(__ATOMIC_ACQUIRE, "agent");   // once: drop stale lines
  __shared__ float Ls[4][16][17];
  __shared__ u16 Lh[4][16][4];              // per-wave h gather for 8B publish
  const int t    = threadIdx.x;
  const int wave = t >> 6, lane = t & 63;
  const int quad = lane >> 4, l16 = lane & 15;
  const int b    = blockIdx.x;
  const int tm   = b & 3;                   // team 0..3
  const int jblk = b >> 2;                  // 0..63 within team
  const int j0   = jblk * 16;               // block's 16 hidden units
  const int jw   = j0 + wave * 4;           // wave's 4 hidden units
  const int env0 = tm * 16;                 // team's 16 envs

  // thread identity: env = env0 + l16, hidden unit j = jw + quad
  const int j = jw + quad;
  const int envg = env0 + l16;
  const float br = bhh[j], bz = bhh[HID + j], bn = bhh[2 * HID + j];
  const u16* giR = giTb + (size_t)j * MROWS;
  const u16* giZ = giTb + (size_t)(HID + j) * MROWS;
  const u16* giN = giTb + (size_t)(2 * HID + j) * MROWS;
  float hp = hxs[(size_t)envg * HID + j];   // register-carried h_prev[env][j]

  unsigned* myflag   = flags + (size_t)b * FLAG_STRIDE;
  unsigned* pollflag = flags + (size_t)(((t & 63) << 2) | tm) * FLAG_STRIDE; // team member (t&63)

  // --- w_hh fragments -> registers (bf16), once. N-cols: gate*4 + jj of jw..jw+3
  bf8 Bfrag[32];
  {
    const int c = l16;                      // c<12: gate=c>>2, jj=c&3; else pad
    const int gate = c >> 2, jj = c & 3;
    const float* wrow = Whh + (size_t)(HID * gate + jw + jj) * HID;
#pragma unroll
    for (int kk = 0; kk < 32; ++kk) {
      bf8 bv = {0, 0, 0, 0, 0, 0, 0, 0};
      if (c < 12) {
        const float* s = wrow + kk * 32 + quad * 8;
#pragma unroll
        for (int e = 0; e < 8; ++e) bv[e] = (short)f2bf(s[e]);
      }
      Bfrag[kk] = bv;
    }
  }

  // prefetched gi/done for step 0
  u16 girv = giR[envg], gizv = giZ[envg], ginv = giN[envg];
  float dnv = done[envg];

  for (int step = 0; step < TSTEPS; ++step) {
    const u16* hsrc = step ? (featb + (size_t)(step - 1) * (NENVS * HID)) : hb0;
    const bf8* Arow = (const bf8*)(hsrc + (size_t)envg * HID) + quad;

    // 32 plain cached A-frag loads (pristine lines -> miss -> fill via MALL)
    bf8 ar[32];
#pragma unroll
    for (int kk = 0; kk < 32; ++kk) ar[kk] = Arow[kk * 4];

    const float ir  = bf2f(girv);
    const float iz  = bf2f(gizv);
    const float in_ = bf2f(ginv);
    const float dn  = dnv;

    f4 acc0 = {0.f, 0.f, 0.f, 0.f};
    f4 acc1 = {0.f, 0.f, 0.f, 0.f};
#pragma unroll
    for (int kk = 0; kk < 32; kk += 2) {
      acc0 = __builtin_amdgcn_mfma_f32_16x16x32_bf16(ar[kk],     Bfrag[kk],     acc0, 0, 0, 0);
      acc1 = __builtin_amdgcn_mfma_f32_16x16x32_bf16(ar[kk + 1], Bfrag[kk + 1], acc1, 0, 0, 0);
    }
    const f4 acc = acc0 + acc1;

    // C-frag (row=env=quad*4+r, col=gatecol=l16) -> LDS (same-wave exchange)
    float* L = &Ls[wave][0][0];
#pragma unroll
    for (int r = 0; r < 4; ++r) L[(quad * 4 + r) * 17 + l16] = acc[r];
    const float m  = 1.0f - dn;
    const float rr = L[l16 * 17 + quad];
    const float zz = L[l16 * 17 + 4 + quad];
    const float nn = L[l16 * 17 + 8 + quad];
    const float hr = m * rr + br;            // dot(m*h,w) == m*dot(h,w)
    const float hz = m * zz + bz;
    const float hn = m * nn + bn;
    const float rg = 1.f / (1.f + __expf(-(ir + hr)));
    const float zg = 1.f / (1.f + __expf(-(iz + hz)));
    const float ng = tanhf(in_ + rg * hn);
    const float hnew = (1.f - zg) * ng + zg * (m * hp);
    hp = hnew;

    // --- publish h at the MALL via agent-scope atomic STORE (no RMW) ---
    Lh[wave][l16][quad] = f2bf(hnew);
    __builtin_amdgcn_wave_barrier();
    if (quad == 0) {
      const u64 hv = *(const u64*)&Lh[wave][l16][0];
      u64* dst = (u64*)(featb + (size_t)(step * 64 + env0 + l16) * HID + jw);
      __hip_atomic_store(dst, hv, __ATOMIC_RELAXED, __HIP_MEMORY_SCOPE_AGENT);
    }

    if (step != TSTEPS - 1) {
      // prefetch next gi/done AFTER the h store (order pinned) so the 4 loads
      // drain under the flag/poll leg instead of inside the vmcnt wait.
      asm volatile("" ::: "memory");                     // no hoist above store
      {
        const int c2 = (step + 1) * 64 + envg;
        girv = giR[c2]; gizv = giZ[c2]; ginv = giN[c2]; dnv = done[c2];
      }
      // wave vmem queue (oldest..newest): [h store][giR][giZ][giN][done]
      asm volatile("s_waitcnt vmcnt(4)" ::: "memory");   // h store at MALL; 4 loads in flight
      __syncthreads();                                   // all waves' stores drained
      if (t == 0)
        __hip_atomic_store(myflag, (unsigned)(step + 1),
                           __ATOMIC_RELAXED, __HIP_MEMORY_SCOPE_AGENT);
      const unsigned tgt = (unsigned)(step + 1);
      if (t < 64) {                                      // wave 0: one lane per teammate
        while (__hip_atomic_load(pollflag, __ATOMIC_RELAXED,
                                 __HIP_MEMORY_SCOPE_AGENT) < tgt) {
          __builtin_amdgcn_s_sleep(1);                   // ~64cy backoff: cut MALL spam
        }
      }
      __syncthreads();                                   // release waves 1..3
      asm volatile("" ::: "memory");         // no hoisting above the barrier
    }
  }
}

// ---------------------------------------------------------------------------
extern "C" void kernel_launch(void* const* d_in, const int* in_sizes, int n_in,
                              void* d_out, int out_size, void* d_ws, size_t ws_size,
                              hipStream_t stream) {
  (void)in_sizes; (void)n_in; (void)out_size; (void)ws_size;
  const float* x     = (const float*)d_in[0];   // [8192][1024]
  const float* hxs   = (const float*)d_in[1];   // [64][1024]
  const float* done  = (const float*)d_in[2];   // [8192]
  const float* w_ih  = (const float*)d_in[3];   // [3072][1024]
  const float* w_hh  = (const float*)d_in[4];   // [3072][1024]
  const float* b_ih  = (const float*)d_in[5];   // [3072]
  const float* b_hh  = (const float*)d_in[6];   // [3072]
  const float* w_out = (const float*)d_in[7];   // [1024][1024]
  const float* b_out = (const float*)d_in[8];   // [1024]
  float* out = (float*)d_out;                   // [8192][1024] ++ [64][1024]

  // ws layout (~92.5 MB): giTb | xb | featb (PRISTINE) | wihb | woutb | hb0 | flags
  u16* giTb  = (u16*)d_ws;                               // [3072][8192] bf16
  u16* xb    = giTb + (size_t)G3 * MROWS;                // [8192][1024] bf16
  u16* featb = xb + (size_t)MROWS * HID;                 // [8192][1024] bf16
  u16* wihb  = featb + (size_t)MROWS * HID;
  u16* woutb = wihb + (size_t)G3 * HID;
  u16* hb0   = woutb + (size_t)HID * HID;
  unsigned* flags = (unsigned*)(hb0 + (size_t)NENVS * HID);  // 256*32 u32

  // casts + flag init
  k_cast4<<<dim3(MROWS * HID / 4 / 256), dim3(256), 0, stream>>>((const float4*)x, (us4*)xb, MROWS * HID / 4);
  k_cast4<<<dim3(G3 * HID / 4 / 256), dim3(256), 0, stream>>>((const float4*)w_ih, (us4*)wihb, G3 * HID / 4);
  k_cast4<<<dim3(HID * HID / 4 / 256), dim3(256), 0, stream>>>((const float4*)w_out, (us4*)woutb, HID * HID / 4);
  k_cast4<<<dim3(NENVS * HID / 4 / 256), dim3(256), 0, stream>>>((const float4*)hxs, (us4*)hb0, NENVS * HID / 4);
  k_zerofl<<<dim3(256 * FLAG_STRIDE / 256), dim3(256), 0, stream>>>(flags);

  // gi = w_ih . x^T + b_ih  -> [3072][8192] bf16   (2-phase + XCD swizzle)
  k_gemm_bf16<u16, 0, 0, 1><<<dim3(MROWS / 128, G3 / 128), dim3(256), 0, stream>>>(
      wihb, xb, b_ih, giTb, MROWS);

  // GRU scan (cooperative for co-residency; sync is team-local flag barrier)
  {
    const u16* giTb_c = giTb; const float* done_c = done; const float* whh_c = w_hh;
    const float* bhh_c = b_hh; const float* hxs_c = hxs;
    const u16* hb0_c = hb0; u16* featb_p = featb; unsigned* flags_p = flags;
    void* args[8] = { (void*)&giTb_c, (void*)&done_c, (void*)&whh_c, (void*)&bhh_c,
                      (void*)&hxs_c, (void*)&hb0_c, (void*)&featb_p, (void*)&flags_p };
    hipLaunchCooperativeKernel(reinterpret_cast<void*>(k_gru_mfma),
                               dim3(256), dim3(256), args, 0, stream);
  }

  // out = relu(feat . w_out^T + b_out) -> [8192][1024] fp32  (2-phase + swizzle)
  k_gemm_bf16<float, 1, 1, 1><<<dim3(HID / 128, MROWS / 128), dim3(256), 0, stream>>>(
      featb, woutb, b_out, out, HID);

  // h_last tail
  k_tail<<<dim3(256), dim3(256), 0, stream>>>(featb, out + (size_t)MROWS * HID);
}

// Round 7
// 714.155 us; speedup vs baseline: 1.7131x; 1.7131x over previous
//
#include <hip/hip_runtime.h>
#include <hip/hip_bf16.h>
#include <cmath>

#define TSTEPS 128
#define NENVS  64
#define HID    1024
#define G3     3072
#define MROWS  8192   // T*N

typedef unsigned short u16;
typedef unsigned long long u64;
typedef short bf8 __attribute__((ext_vector_type(8)));   // 8 bf16 = 4 VGPRs
typedef float f4  __attribute__((ext_vector_type(4)));   // MFMA acc
typedef u16  us4  __attribute__((ext_vector_type(4)));

#define FLAG_STRIDE 32   // u32s between flags (128 B) — no same-line RMW collisions

static __device__ inline u16 f2bf(float f) {
  __hip_bfloat16 h = __float2bfloat16(f);   // RNE
  return *reinterpret_cast<u16*>(&h);
}
static __device__ inline float bf2f(u16 v) {
  __hip_bfloat16 h = *reinterpret_cast<__hip_bfloat16*>(&v);
  return __bfloat162float(h);
}

// async global->LDS, 16B per lane; LDS dest = wave-uniform base + lane*16
static __device__ inline void gload16(const u16* g, u16* l) {
  __builtin_amdgcn_global_load_lds(
      (const __attribute__((address_space(1))) void*)g,
      (__attribute__((address_space(3))) void*)l, 16, 0, 0);
}

// ---------------------------------------------------------------------------
// fp32 -> bf16 cast, 4 elements/thread
__global__ __launch_bounds__(256) void k_cast4(const float4* __restrict__ src,
                                               us4* __restrict__ dst, int n4) {
  int i = blockIdx.x * 256 + threadIdx.x;
  if (i < n4) {
    float4 v = src[i];
    us4 o = { f2bf(v.x), f2bf(v.y), f2bf(v.z), f2bf(v.w) };
    dst[i] = o;
  }
}

// zero the flag array (8192 u32 = 32 KB); runtime's end-of-kernel writeback
// makes the zeros MALL/DRAM-visible before the scan.
__global__ __launch_bounds__(256) void k_zerofl(unsigned* __restrict__ p) {
  p[blockIdx.x * 256 + threadIdx.x] = 0u;
}

// out_tail[n][k] = float(featb_last[n][k])
__global__ __launch_bounds__(256) void k_tail(const u16* __restrict__ featb,
                                              float* __restrict__ dst) {
  __builtin_amdgcn_fence(__ATOMIC_ACQUIRE, "agent");   // defensive: kill stale lines
  int i = blockIdx.x * 256 + threadIdx.x;   // 0..65535
  dst[i] = bf2f(featb[(size_t)(TSTEPS - 1) * NENVS * HID + i]);
}

// ---------------------------------------------------------------------------
// bf16 MFMA GEMM (FROZEN since R3): C = A.B^T + bias (+relu), 128x128 tile,
// BK=32, 2x2 waves, 2-phase double-buffered LDS, (256,4) co-residency.
// SWZ: bijective XCD-chunk swizzle (requires nwg % 8 == 0).
template<typename CT, int BIAS_PER_N, int RELU, int SWZ>
__global__ __launch_bounds__(256, 4) void k_gemm_bf16(const u16* __restrict__ A,
                                                      const u16* __restrict__ B,
                                                      const float* __restrict__ bias,
                                                      CT* __restrict__ C, int ldc) {
  __builtin_amdgcn_fence(__ATOMIC_ACQUIRE, "agent");   // defensive (cheap, once)
  __shared__ u16 ldsA[2][128 * 32];    // [buf][row 128][k 32], 2 x 8 KB
  __shared__ u16 ldsB[2][128 * 32];
  const int t = threadIdx.x, wave = t >> 6, lane = t & 63;
  const int quad = lane >> 4, l16 = lane & 15;
  const int wm = wave >> 1, wn = wave & 1;       // 2x2 wave grid
  int bx = blockIdx.x, by = blockIdx.y;
  if (SWZ) {
    const unsigned nwg = gridDim.x * gridDim.y;
    const unsigned L = (unsigned)by * gridDim.x + bx;
    const unsigned w = (L & 7u) * (nwg >> 3) + (L >> 3);   // XCD gets contiguous chunk
    bx = (int)(w % gridDim.x); by = (int)(w / gridDim.x);
  }
  const int m0 = by * 128;
  const int n0 = bx * 128;

  const int c   = wave * 128 + lane;
  const int row = c >> 2, k8 = c & 3;
  const u16* gA0 = A + (size_t)(m0 + row) * HID + k8 * 8;
  const u16* gA1 = gA0 + (size_t)16 * HID;       // chunk c+64 -> row+16, same k8
  const u16* gB0 = B + (size_t)(n0 + row) * HID + k8 * 8;
  const u16* gB1 = gB0 + (size_t)16 * HID;
  const int lw = wave * 1024;                    // wave-uniform LDS chunk base (u16)

  f4 acc[4][4];
#pragma unroll
  for (int mt = 0; mt < 4; ++mt)
#pragma unroll
    for (int nt = 0; nt < 4; ++nt) acc[mt][nt] = (f4){0.f, 0.f, 0.f, 0.f};

  const int aoff0 = (wm * 64 + l16) * 32 + quad * 8;
  const int boff0 = (wn * 64 + l16) * 32 + quad * 8;

  gload16(gA0, &ldsA[0][lw]);
  gload16(gA1, &ldsA[0][lw + 512]);
  gload16(gB0, &ldsB[0][lw]);
  gload16(gB1, &ldsB[0][lw + 512]);
  __syncthreads();

  int cur = 0;
  for (int kb = 0; kb < 32; ++kb) {
    if (kb < 31) {
      const int ko = (kb + 1) * 32;
      const int nb = cur ^ 1;
      gload16(gA0 + ko, &ldsA[nb][lw]);
      gload16(gA1 + ko, &ldsA[nb][lw + 512]);
      gload16(gB0 + ko, &ldsB[nb][lw]);
      gload16(gB1 + ko, &ldsB[nb][lw + 512]);
    }
    bf8 af[4], bfr[4];
#pragma unroll
    for (int mt = 0; mt < 4; ++mt)
      af[mt] = *(const bf8*)(&ldsA[cur][0] + aoff0 + mt * 16 * 32);
#pragma unroll
    for (int nt = 0; nt < 4; ++nt)
      bfr[nt] = *(const bf8*)(&ldsB[cur][0] + boff0 + nt * 16 * 32);
#pragma unroll
    for (int mt = 0; mt < 4; ++mt)
#pragma unroll
      for (int nt = 0; nt < 4; ++nt)
        acc[mt][nt] = __builtin_amdgcn_mfma_f32_16x16x32_bf16(
            af[mt], bfr[nt], acc[mt][nt], 0, 0, 0);
    if (kb < 31) {
      __syncthreads();
      cur ^= 1;
    }
  }

#pragma unroll
  for (int mt = 0; mt < 4; ++mt)
#pragma unroll
    for (int nt = 0; nt < 4; ++nt) {
      const int n = n0 + wn * 64 + nt * 16 + l16;
      const float bn = BIAS_PER_N ? bias[n] : 0.f;
#pragma unroll
      for (int r = 0; r < 4; ++r) {
        const int m = m0 + wm * 64 + mt * 16 + quad * 4 + r;
        float v = acc[mt][nt][r] + (BIAS_PER_N ? bn : bias[m]);
        if (RELU) v = fmaxf(v, 0.f);
        if constexpr (sizeof(CT) == 2)
          C[(size_t)m * ldc + n] = (CT)f2bf(v);
        else
          C[(size_t)m * ldc + n] = v;
      }
    }
}

// ---------------------------------------------------------------------------
// MFMA GRU scan (R4 protocol, LDS-staged A-tile). 4 teams x 64 blocks; team
// tm owns envs tm*16..+15; block = 16 envs x 16 j (wave = 4 j).
// NEW: the 32KB A-tile (16 env rows x 1024 bf16) is staged ONCE per block via
// global_load_lds (8 calls/thread) instead of each wave flat-loading it
// (kills the 4x redundant 128KB/block/step = 32MB/step fill traffic).
// Swizzle (rule #21, both sides): LDS slot s holds global chunk
// (env=s>>7, kc=(s&127)^(env&7)) — achieved by pre-swizzling the per-lane
// GLOBAL source (dest stays linear); ds_read applies the same XOR. Bank
// spread = uniform 8 lanes/4-bank group (physical optimum for wave64 b128).
// Sync protocol byte-identical to R4 (proven 886us): publish via returning
// agent atomic exchange; vmcnt(0)+syncthreads; flag exchange; wave-0 spin
// with s_sleep; syncthreads release.
__global__ __launch_bounds__(256, 1) void k_gru_mfma(
    const u16*  __restrict__ giTb,          // [3072][8192] bf16
    const float* __restrict__ done,         // [8192]
    const float* __restrict__ Whh,          // [3072][1024]
    const float* __restrict__ bhh,          // [3072]
    const float* __restrict__ hxs,          // [64][1024] fp32
    const u16*  __restrict__ hb0,           // [64][1024] bf16 h0
    u16*        __restrict__ featb,         // [8192][1024] bf16, PRISTINE region
    unsigned*   __restrict__ flags) {       // [256*FLAG_STRIDE] u32, zeroed
  __builtin_amdgcn_fence(__ATOMIC_ACQUIRE, "agent");   // once: drop stale lines
  __shared__ u16 stg[16 * 1024];            // 32KB staged A-tile (swizzled chunks)
  __shared__ float Ls[4][16][17];
  __shared__ u16 Lh[4][16][4];              // per-wave h gather for 8B publish
  const int t    = threadIdx.x;
  const int wave = t >> 6, lane = t & 63;
  const int quad = lane >> 4, l16 = lane & 15;
  const int b    = blockIdx.x;
  const int tm   = b & 3;                   // team 0..3
  const int jblk = b >> 2;                  // 0..63 within team
  const int j0   = jblk * 16;               // block's 16 hidden units
  const int jw   = j0 + wave * 4;           // wave's 4 hidden units
  const int env0 = tm * 16;                 // team's 16 envs

  // thread identity: env = env0 + l16, hidden unit j = jw + quad
  const int j = jw + quad;
  const int envg = env0 + l16;
  const float br = bhh[j], bz = bhh[HID + j], bn = bhh[2 * HID + j];
  const u16* giR = giTb + (size_t)j * MROWS;
  const u16* giZ = giTb + (size_t)(HID + j) * MROWS;
  const u16* giN = giTb + (size_t)(2 * HID + j) * MROWS;
  float hp = hxs[(size_t)envg * HID + j];   // register-carried h_prev[env][j]

  unsigned* myflag   = flags + (size_t)b * FLAG_STRIDE;
  unsigned* pollflag = flags + (size_t)(((t & 63) << 2) | tm) * FLAG_STRIDE; // team member (t&63)

  // --- staging identity (step-invariant): call q stages LDS slot
  // slotq = wave*512 + q*64 + lane; global chunk = (env0 + slotq>>7,
  // kc = (slotq&127) ^ ((slotq>>7)&7)); u16 offset within the 64-row h slab:
  unsigned goff[8];
#pragma unroll
  for (int q = 0; q < 8; ++q) {
    const int slotq = wave * 512 + q * 64 + lane;
    const int envl  = slotq >> 7;           // 0..15 team-local row
    const int kc    = (slotq & 127) ^ (envl & 7);
    goff[q] = (unsigned)((env0 + envl) * HID + kc * 8);
  }
  // --- ds_read bases (step-invariant): reader (l16, quad, kk) hits slot
  // l16*128 + 4*(kk ^ b2) + (quad ^ (l16&3)), b2 = (l16>>2)&1.
  const int b2 = (l16 >> 2) & 1;
  const u16* sb  = stg + l16 * 1024 + (quad ^ (l16 & 3)) * 8;
  const u16* sbE = sb + (b2 << 5);          // even kk: +32*b2 u16
  const u16* sbO = sb - (b2 << 5);          // odd  kk: -32*b2 u16

  // --- w_hh fragments -> registers (bf16), once. N-cols: gate*4 + jj of jw..jw+3
  bf8 Bfrag[32];
  {
    const int c = l16;                      // c<12: gate=c>>2, jj=c&3; else pad
    const int gate = c >> 2, jj = c & 3;
    const float* wrow = Whh + (size_t)(HID * gate + jw + jj) * HID;
#pragma unroll
    for (int kk = 0; kk < 32; ++kk) {
      bf8 bv = {0, 0, 0, 0, 0, 0, 0, 0};
      if (c < 12) {
        const float* s = wrow + kk * 32 + quad * 8;
#pragma unroll
        for (int e = 0; e < 8; ++e) bv[e] = (short)f2bf(s[e]);
      }
      Bfrag[kk] = bv;
    }
  }

  // prefetched gi/done for step 0
  u16 girv = giR[envg], gizv = giZ[envg], ginv = giN[envg];
  float dnv = done[envg];

  for (int step = 0; step < TSTEPS; ++step) {
    const u16* hsrc = step ? (featb + (size_t)(step - 1) * (NENVS * HID)) : hb0;

    // --- stage A-tile once per block: 8 x global_load_lds(16B)/thread ---
#pragma unroll
    for (int q = 0; q < 8; ++q)
      gload16(hsrc + goff[q], stg + wave * 4096 + q * 512);
    asm volatile("s_waitcnt vmcnt(0)" ::: "memory");     // fills in LDS
    __syncthreads();                                     // visible to all waves

    // --- A-frags from LDS (swizzled ds_read_b128, compile-time offsets) ---
    bf8 ar[32];
#pragma unroll
    for (int kk = 0; kk < 32; kk += 2) {
      ar[kk]     = *(const bf8*)(sbE + kk * 32);
      ar[kk + 1] = *(const bf8*)(sbO + (kk + 1) * 32);
    }

    const float ir  = bf2f(girv);
    const float iz  = bf2f(gizv);
    const float in_ = bf2f(ginv);
    const float dn  = dnv;

    f4 acc0 = {0.f, 0.f, 0.f, 0.f};
    f4 acc1 = {0.f, 0.f, 0.f, 0.f};
#pragma unroll
    for (int kk = 0; kk < 32; kk += 2) {
      acc0 = __builtin_amdgcn_mfma_f32_16x16x32_bf16(ar[kk],     Bfrag[kk],     acc0, 0, 0, 0);
      acc1 = __builtin_amdgcn_mfma_f32_16x16x32_bf16(ar[kk + 1], Bfrag[kk + 1], acc1, 0, 0, 0);
    }
    const f4 acc = acc0 + acc1;

    // C-frag (row=env=quad*4+r, col=gatecol=l16) -> LDS (same-wave exchange)
    float* L = &Ls[wave][0][0];
#pragma unroll
    for (int r = 0; r < 4; ++r) L[(quad * 4 + r) * 17 + l16] = acc[r];
    const float m  = 1.0f - dn;
    const float rr = L[l16 * 17 + quad];
    const float zz = L[l16 * 17 + 4 + quad];
    const float nn = L[l16 * 17 + 8 + quad];
    const float hr = m * rr + br;            // dot(m*h,w) == m*dot(h,w)
    const float hz = m * zz + bz;
    const float hn = m * nn + bn;
    const float rg = 1.f / (1.f + __expf(-(ir + hr)));
    const float zg = 1.f / (1.f + __expf(-(iz + hz)));
    const float ng = tanhf(in_ + rg * hn);
    const float hnew = (1.f - zg) * ng + zg * (m * hp);
    hp = hnew;

    // prefetch next step's gi/done (drains under the same vmcnt(0) as h swaps)
    if (step + 1 < TSTEPS) {
      const int c2 = (step + 1) * 64 + envg;
      girv = giR[c2]; gizv = giZ[c2]; ginv = giN[c2]; dnv = done[c2];
    }

    // --- publish h at the MALL via returning atomic swap (8B/env/wave) ---
    Lh[wave][l16][quad] = f2bf(hnew);
    __builtin_amdgcn_wave_barrier();
    if (quad == 0) {
      const u64 hv = *(const u64*)&Lh[wave][l16][0];
      u64* dst = (u64*)(featb + (size_t)(step * 64 + env0 + l16) * HID + jw);
      u64 old = __hip_atomic_exchange(dst, hv, __ATOMIC_RELAXED, __HIP_MEMORY_SCOPE_AGENT);
      asm volatile("" :: "v"(old));          // keep returning form: ack = at MALL
    }

    if (step != TSTEPS - 1) {
      asm volatile("s_waitcnt vmcnt(0)" ::: "memory");   // h swaps done at MALL
      __syncthreads();                                   // all waves drained
      if (t == 0) {
        unsigned old = __hip_atomic_exchange(myflag, (unsigned)(step + 1),
                                             __ATOMIC_RELAXED, __HIP_MEMORY_SCOPE_AGENT);
        asm volatile("" :: "v"(old));
      }
      const unsigned tgt = (unsigned)(step + 1);
      if (t < 64) {                                      // wave 0: one lane per teammate
        while (__hip_atomic_load(pollflag, __ATOMIC_RELAXED,
                                 __HIP_MEMORY_SCOPE_AGENT) < tgt) {
          __builtin_amdgcn_s_sleep(1);                   // ~64cy backoff: cut MALL spam
        }
      }
      __syncthreads();                                   // release waves 1..3
      asm volatile("" ::: "memory");         // no hoisting above the barrier
    }
  }
}

// ---------------------------------------------------------------------------
extern "C" void kernel_launch(void* const* d_in, const int* in_sizes, int n_in,
                              void* d_out, int out_size, void* d_ws, size_t ws_size,
                              hipStream_t stream) {
  (void)in_sizes; (void)n_in; (void)out_size; (void)ws_size;
  const float* x     = (const float*)d_in[0];   // [8192][1024]
  const float* hxs   = (const float*)d_in[1];   // [64][1024]
  const float* done  = (const float*)d_in[2];   // [8192]
  const float* w_ih  = (const float*)d_in[3];   // [3072][1024]
  const float* w_hh  = (const float*)d_in[4];   // [3072][1024]
  const float* b_ih  = (const float*)d_in[5];   // [3072]
  const float* b_hh  = (const float*)d_in[6];   // [3072]
  const float* w_out = (const float*)d_in[7];   // [1024][1024]
  const float* b_out = (const float*)d_in[8];   // [1024]
  float* out = (float*)d_out;                   // [8192][1024] ++ [64][1024]

  // ws layout (~92.5 MB): giTb | xb | featb (PRISTINE) | wihb | woutb | hb0 | flags
  u16* giTb  = (u16*)d_ws;                               // [3072][8192] bf16
  u16* xb    = giTb + (size_t)G3 * MROWS;                // [8192][1024] bf16
  u16* featb = xb + (size_t)MROWS * HID;                 // [8192][1024] bf16
  u16* wihb  = featb + (size_t)MROWS * HID;
  u16* woutb = wihb + (size_t)G3 * HID;
  u16* hb0   = woutb + (size_t)HID * HID;
  unsigned* flags = (unsigned*)(hb0 + (size_t)NENVS * HID);  // 256*32 u32

  // casts + flag init
  k_cast4<<<dim3(MROWS * HID / 4 / 256), dim3(256), 0, stream>>>((const float4*)x, (us4*)xb, MROWS * HID / 4);
  k_cast4<<<dim3(G3 * HID / 4 / 256), dim3(256), 0, stream>>>((const float4*)w_ih, (us4*)wihb, G3 * HID / 4);
  k_cast4<<<dim3(HID * HID / 4 / 256), dim3(256), 0, stream>>>((const float4*)w_out, (us4*)woutb, HID * HID / 4);
  k_cast4<<<dim3(NENVS * HID / 4 / 256), dim3(256), 0, stream>>>((const float4*)hxs, (us4*)hb0, NENVS * HID / 4);
  k_zerofl<<<dim3(256 * FLAG_STRIDE / 256), dim3(256), 0, stream>>>(flags);

  // gi = w_ih . x^T + b_ih  -> [3072][8192] bf16   (2-phase + XCD swizzle)
  k_gemm_bf16<u16, 0, 0, 1><<<dim3(MROWS / 128, G3 / 128), dim3(256), 0, stream>>>(
      wihb, xb, b_ih, giTb, MROWS);

  // GRU scan (cooperative for co-residency; sync is team-local flag barrier)
  {
    const u16* giTb_c = giTb; const float* done_c = done; const float* whh_c = w_hh;
    const float* bhh_c = b_hh; const float* hxs_c = hxs;
    const u16* hb0_c = hb0; u16* featb_p = featb; unsigned* flags_p = flags;
    void* args[8] = { (void*)&giTb_c, (void*)&done_c, (void*)&whh_c, (void*)&bhh_c,
                      (void*)&hxs_c, (void*)&hb0_c, (void*)&featb_p, (void*)&flags_p };
    hipLaunchCooperativeKernel(reinterpret_cast<void*>(k_gru_mfma),
                               dim3(256), dim3(256), args, 0, stream);
  }

  // out = relu(feat . w_out^T + b_out) -> [8192][1024] fp32  (2-phase + swizzle)
  k_gemm_bf16<float, 1, 1, 1><<<dim3(HID / 128, MROWS / 128), dim3(256), 0, stream>>>(
      featb, woutb, b_out, out, HID);

  // h_last tail
  k_tail<<<dim3(256), dim3(256), 0, stream>>>(featb, out + (size_t)MROWS * HID);
}